// Round 14
// baseline (2447.976 us; speedup 1.0000x reference)
//
#include <hip/hip_runtime.h>
#include <math.h>

#define NZ 32
#define NY 360
#define NX 720
#define NXU (NX + 1)   // 721
#define NYV (NY + 1)   // 361
#define SU (NY * NXU)
#define SV (NYV * NX)
#define SW (NY * NX)
#define UVZS 4
#define UVZB (NZ / UVZS)   // 8
#define TZS 2
#define TZB (NZ / TZS)     // 16
#define PZ 4
#define PZB (NZ / PZ)
#define NBU (12 * 90 * UVZS)   // 4320
#define NBV (12 * 91 * UVZS)   // 4368
#define NBT (3 * NY * TZS)     // 2160

static constexpr double PI_D = 3.14159265358979323846;
static constexpr double RE_D = 6400000.0;
static constexpr double DX_D = 2.0 * PI_D / NX;
static constexpr double DY_D = PI_D / NY;
static constexpr double DA_D = RE_D * DX_D * (RE_D * DY_D);

constexpr float FXC   = (float)(0.25 * RE_D * DY_D);
constexpr float GXC   = (float)(0.25 * RE_D * DX_D);
constexpr float DAF   = (float)DA_D;
constexpr float DA8F  = (float)(DA_D / 8.0);
constexpr float DYF   = (float)DY_D;
constexpr float DXF   = (float)DX_D;
constexpr float CPDF  = 1004.67f;
constexpr float DIFFF = 1.0e9f;
constexpr float RDZF  = 32.0f;
constexpr float DZF   = 0.03125f;
constexpr float K1    = 0.25f / 12.0f;
constexpr float K2u   = 0.25f / 24.0f;
constexpr float K2v   = 0.5f / 24.0f;

__device__ __forceinline__ int wr(int i, int n) {
    return i < 0 ? i + n : (i >= n ? i - n : i);
}

__device__ __forceinline__ int imin(int a, int b) { return a < b ? a : b; }

__device__ __forceinline__ int xcd_swz(int bid, int nwg) {
    int q = nwg >> 3, r = nwg & 7;
    int xcd = bid & 7, off = bid >> 3;
    return (xcd < r ? xcd * (q + 1) : r * (q + 1) + (xcd - r) * q) + off;
}

// async global->LDS DMA, 4B/lane. LDS dest = wave-uniform base + lane*4.
__device__ __forceinline__ void gl_lds(const float* g, float* l) {
    __builtin_amdgcn_global_load_lds(
        (const __attribute__((address_space(1))) void*)g,
        (__attribute__((address_space(3))) void*)l,
        4, 0, 0);
}

__global__ void k_cosy(const float* __restrict__ Y, float* __restrict__ cy) {
    int t = threadIdx.x;
    if (t < NYV) cy[t] = cosf(Y[t]);
}

__global__ __launch_bounds__(256, 8) void k_pi1_part(
        const float* __restrict__ pi, const float* __restrict__ u,
        const float* __restrict__ v, const float* __restrict__ cy,
        float* __restrict__ part) {
    int x = blockIdx.x * blockDim.x + threadIdx.x;
    int y = blockIdx.y;
    int bz = blockIdx.z;
    if (x >= NX) return;
    int xm = wr(x - 1, NX), xp = wr(x + 1, NX);
    float pc  = pi[y * NX + x];
    float a_m = FXC * (pi[y * NX + xm] + pc);
    float a_p = FXC * (pc + pi[y * NX + xp]);
    float g_lo = GXC * (pi[wr(y - 1, NY) * NX + x] + pc) * cy[y];
    float g_hi = GXC * (pc + pi[wr(y + 1, NY) * NX + x]) * cy[y + 1];
    float acc = 0.f;
    int z0 = bz * PZB;
#pragma unroll
    for (int iz = 0; iz < PZB; ++iz) {
        int z = z0 + iz;
        float fxm = a_m * u[((size_t)z * NY + y) * NXU + x];
        float fxp = a_p * u[((size_t)z * NY + y) * NXU + x + 1];
        float glo = g_lo * v[((size_t)z * NYV + y) * NX + x];
        float ghi = g_hi * v[((size_t)z * NYV + y + 1) * NX + x];
        acc += ((fxp - fxm) + (ghi - glo)) * DZF;
    }
    part[(size_t)bz * SW + y * NX + x] = acc;
}

__global__ __launch_bounds__(256, 8) void k_pi1_fin(
        const float* __restrict__ part, const float* __restrict__ pi0,
        const float* __restrict__ dtp, float dtmul, float* __restrict__ out) {
    int x = blockIdx.x * blockDim.x + threadIdx.x;
    int y = blockIdx.y;
    if (x >= NX) return;
    float dt = dtp[0] * dtmul;
    int i = y * NX + x;
    float s = part[i] + part[SW + i] + part[2 * SW + i] + part[3 * SW + i];
    out[i] = pi0[i] - dt / DAF * s;
}

__global__ __launch_bounds__(256, 8) void k_theta1(
        const float* __restrict__ pi, const float* __restrict__ th,
        const float* __restrict__ u, const float* __restrict__ v,
        const float* __restrict__ cy, const float* __restrict__ w,
        const float* __restrict__ pi0, const float* __restrict__ th0,
        const float* __restrict__ pi1, const float* __restrict__ dtp,
        float dtmul, float* __restrict__ out) {
    int wgid = xcd_swz(blockIdx.x, NBT);
    int bx = wgid % 3; int tmp = wgid / 3;
    int y = tmp % NY; int bz = tmp / NY;
    int x = bx * 256 + threadIdx.x;
    if (x >= NX) return;
    float dt = dtp[0] * dtmul;
    int xm = wr(x - 1, NX), xp = wr(x + 1, NX);
    int ym = wr(y - 1, NY), yp = wr(y + 1, NY);
    float pc  = pi[y * NX + x];
    float a_m = FXC * (pi[y * NX + xm] + pc);
    float a_p = FXC * (pc + pi[y * NX + xp]);
    float g_lo = GXC * (pi[ym * NX + x] + pc) * cy[y];
    float g_hi = GXC * (pc + pi[yp * NX + x]) * cy[y + 1];
    float rp1  = 1.0f / pi1[y * NX + x];
    float c0v  = pi0[y * NX + x] * rp1;
    float cvert = pc * DAF * RDZF;
    float cdt  = dt / DAF * rp1;
    int base = y * NX + x;
    int z0 = bz * TZB;
    float tc  = th[(size_t)z0 * SW + base];
    float tzm = (z0 > 0) ? th[(size_t)(z0 - 1) * SW + base] : 0.f;
#pragma unroll 4
    for (int iz = 0; iz < TZB; ++iz) {
        int z = z0 + iz;
        const float* tb = th + (size_t)z * SW;
        float tzp = (z + 1 < NZ) ? tb[SW + base] : 0.f;
        float t_xm = tb[y * NX + xm], t_xp = tb[y * NX + xp];
        float t_ym = tb[ym * NX + x], t_yp = tb[yp * NX + x];
        float fx0 = a_m * u[((size_t)z * NY + y) * NXU + x];
        float fx1 = a_p * u[((size_t)z * NY + y) * NXU + x + 1];
        float gg0 = g_lo * v[((size_t)z * NYV + y) * NX + x];
        float gg1 = g_hi * v[((size_t)z * NYV + y + 1) * NX + x];
        float adv = (fx1 * 0.5f * (tc + t_xp) - fx0 * 0.5f * (t_xm + tc)
                   + gg1 * 0.5f * (tc + t_yp) - gg0 * 0.5f * (t_ym + tc)) * 0.5f;
        float th0v = th0[(size_t)z * SW + base];
        float vert = cvert * (w[(size_t)z * SW + base] * th0v);
        float lap = tzp + tzm + t_yp + t_ym + t_xp + t_xm - 6.0f * tc;
        out[(size_t)z * SW + base] = c0v * th0v + cdt * (adv + vert + DIFFF * lap);
        tzm = tc; tc = tzp;
    }
}

// ---------------- k_u1: async DMA single-buffer LDS, UVZS=4, 8 waves/EU ----------------
__global__ __launch_bounds__(256, 8) void k_u1(
        const float* __restrict__ pi, const float* __restrict__ th,
        const float* __restrict__ u, const float* __restrict__ v,
        const float* __restrict__ cy, const float* __restrict__ w,
        const float* __restrict__ phi, const float* __restrict__ pi0,
        const float* __restrict__ u0, const float* __restrict__ pi1,
        const float* __restrict__ sigma, const float* __restrict__ Pu,
        const float* __restrict__ Pp, const float* __restrict__ dtp,
        float dtmul, float* __restrict__ out) {
    // layout (floats): su[0:512) svs[512:1024) sws[1024:1536) sts[1536:2048) sps[2048:2560)
    __shared__ float lds[2560];

    const int tx = threadIdx.x, ty = threadIdx.y;
    const int t = ty * 64 + tx;
    int wgid = xcd_swz(blockIdx.x, NBU);
    int bxi = wgid % 12; int tmp = wgid / 12;
    int by = tmp % 90; int bz = tmp / 90;
    const int X0 = bxi * 64, Y = by * 4, z0 = bz * UVZB;

    const int x = X0 + tx;
    const bool act = (x < NXU);
    const int xe = act ? x : NX;
    const int y = Y + ty;
    const float dt = dtp[0] * dtmul;

    const int x0 = wr(xe, NX), xm = wr(xe - 1, NX);
    const int ym = wr(y - 1, NY), yp = wr(y + 1, NY);
    const int c0 = xm, c1 = xm + 1, c2 = x0, c3 = x0 + 1;

    // ---- z-invariant staging offsets (clamped duplicates in pad region) ----
    int o_su[2], o_sv[2], o_sw[2], o_st[2];
#pragma unroll
    for (int c = 0; c < 2; ++c) {
        int i, r, j;
        i = imin(t + c * 256, 401); r = i / 67; j = i - r * 67;
        o_su[c] = wr(Y - 1 + r, NY) * NXU + wr(X0 - 1 + j, NXU);
        i = imin(t + c * 256, 461); r = i / 66; j = i - r * 66;
        o_sv[c] = wr(Y - 1 + r, NYV) * NX + wr(X0 - 1 + j, NX);
        i = imin(t + c * 256, 395); r = i / 66; j = i - r * 66;
        o_sw[c] = wr(Y - 1 + r, NY) * NX + wr(X0 - 1 + j, NX);
        i = imin(t + c * 256, 263); r = i / 66; j = i - r * 66;
        o_st[c] = (Y + r) * NX + wr(X0 - 1 + j, NX);
    }

    // ---- z-invariant pi coefficients ----
    float Px[3][4];
    {
        int rows3[3] = {ym, y, yp};
        int cols4[4] = {c0, c1, c2, c3};
#pragma unroll
        for (int r = 0; r < 3; ++r) {
            int rb = rows3[r] * NX;
#pragma unroll
            for (int c = 0; c < 4; ++c) {
                int cc = cols4[c];
                Px[r][c] = FXC * (pi[rb + wr(cc - 1, NX)] + pi[rb + wr(cc, NX)]);
            }
        }
    }
    float Pg[4][2];
#pragma unroll
    for (int j = 0; j < 4; ++j) {
        int grow = wr(Y - 1 + ty + j, NYV);
        int ra = wr(grow - 1, NY) * NX;
        int rb = wr(grow, NY) * NX;
        float cj = cy[grow];
        Pg[j][0] = GXC * (pi[ra + xm] + pi[rb + xm]) * cj;
        Pg[j][1] = GXC * (pi[ra + x0] + pi[rb + x0]) * cj;
    }
    const float pimm = pi[ym * NX + xm], pim0 = pi[ym * NX + x0];
    const float pipm = pi[yp * NX + xm], pip0 = pi[yp * NX + x0];
    const float dpi  = pi[y * NX + x0] - pi[y * NX + xm];
    const float p0da = DA8F * 0.25f * (pi0[ym * NX + xm] + pi0[ym * NX + x0] + pi0[yp * NX + xm] + pi0[yp * NX + x0]);
    const float p1da = DA8F * 0.25f * (pi1[ym * NX + xm] + pi1[ym * NX + x0] + pi1[yp * NX + xm] + pi1[yp * NX + x0]);
    const float rp1da = 1.0f / p1da;

    const int uidx = y * NXU + xe;
    const int jc1 = (xe == 0) ? tx : tx + 1;
    const int jc2 = (xe < NX) ? tx + 1 : tx + 2;

#define U1_STAGE(zz) { \
    const float* ub_ = u  + (size_t)(zz) * SU; \
    const float* vb_ = v  + (size_t)(zz) * SV; \
    const float* wb_ = w  + (size_t)(zz) * SW; \
    const float* tb_ = th + (size_t)(zz) * SW; \
    const float* pb_ = phi+ (size_t)(zz) * SW; \
    float* Lb = lds + ty * 64; \
    gl_lds(ub_ + o_su[0], Lb);        gl_lds(ub_ + o_su[1], Lb + 256); \
    gl_lds(vb_ + o_sv[0], Lb + 512);  gl_lds(vb_ + o_sv[1], Lb + 768); \
    gl_lds(wb_ + o_sw[0], Lb + 1024); gl_lds(wb_ + o_sw[1], Lb + 1280); \
    gl_lds(tb_ + o_st[0], Lb + 1536); gl_lds(tb_ + o_st[1], Lb + 1792); \
    gl_lds(pb_ + o_st[0], Lb + 2048); gl_lds(pb_ + o_st[1], Lb + 2304); }

    float uzm = (z0 > 0) ? u[(size_t)(z0 - 1) * SU + uidx] : 0.f;

    for (int iz = 0; iz < UVZB; ++iz) {
        const int z = z0 + iz;
        U1_STAGE(z);                                        // async DMA issue
        const float* ub = u + (size_t)z * SU;               // xe==0 patch + ring
        float r_uzp = (z + 1 < NZ) ? ub[SU + uidx] : 0.f;
        __syncthreads();                                    // drain DMA + join

        const float* su  = lds;
        const float* svs = lds + 512;
        const float* sws = lds + 1024;
        const float* sts = lds + 1536;
        const float* sps = lds + 2048;
        {
            const float* su0 = su + ty * 67;
            const float* su1 = su + (ty + 1) * 67;
            const float* su2 = su + (ty + 2) * 67;
            float U00 = su0[tx], U01 = su0[jc1], U02 = su0[jc2], U03 = su0[jc2 + 1], C0v = su0[tx + 1];
            float U10 = su1[tx], U11 = su1[jc1], U12 = su1[jc2], U13 = su1[jc2 + 1], C1v = su1[tx + 1];
            float U20 = su2[tx], U21 = su2[jc1], U22 = su2[jc2], U23 = su2[jc2 + 1], C2v = su2[tx + 1];
            float ulm = U10;
            float ulp = (xe < NX) ? U13 : U12;
            if (xe == 0) {
                U00 = ub[ym * NXU + (NX - 1)];
                U10 = ub[y  * NXU + (NX - 1)];
                U20 = ub[yp * NXU + (NX - 1)];
            }

            float F00 = Px[0][0]*U00, F01 = Px[0][1]*U01, F02 = Px[0][2]*U02, F03 = Px[0][3]*U03;
            float F10 = Px[1][0]*U10, F11 = Px[1][1]*U11, F12 = Px[1][2]*U12, F13 = Px[1][3]*U13;
            float F20 = Px[2][0]*U20, F21 = Px[2][1]*U21, F22 = Px[2][2]*U22, F23 = Px[2][3]*U23;

            const float* pv0 = svs + (ty + 0) * 66;
            const float* pv1 = svs + (ty + 1) * 66;
            const float* pv2 = svs + (ty + 2) * 66;
            const float* pv3 = svs + (ty + 3) * 66;
            float G00 = Pg[0][0]*pv0[tx], G01 = Pg[0][1]*pv0[tx + 1];
            float G10 = Pg[1][0]*pv1[tx], G11 = Pg[1][1]*pv1[tx + 1];
            float G20 = Pg[2][0]*pv2[tx], G21 = Pg[2][1]*pv2[tx + 1];
            float G30 = Pg[3][0]*pv3[tx], G31 = Pg[3][1]*pv3[tx + 1];

            float B0 = (F02 + F03 + F22 + F23) * K1;
            float Bm = (F00 + F01 + F20 + F21) * K1;
            float term1 = Bm * 0.5f * (U10 + U11) - B0 * 0.5f * (U12 + U13);

            float Cp = (G10 + G11 + G30 + G31) * K1;
            float C0t = (G00 + G01 + G20 + G21) * K1;
            float term2 = C0t * 0.5f * (C0v + C1v) - Cp * 0.5f * (C1v + C2v);

            float D_a = 0.5f * (G11 + G31) + (F12 + F13 + F22 + F23) * K2u;
            float D_b = 0.5f * (G00 + G20) + (F00 + F01 + F10 + F11) * K2u;
            float E_c = 0.5f * (G10 + G30) - (F10 + F11 + F20 + F21) * K2u;
            float E_d = 0.5f * (G01 + G21) - (F02 + F03 + F12 + F13) * K2u;
            float term3 = D_a * 0.25f * (U12 + U13 + U22 + U23) - D_b * 0.25f * (U00 + U01 + U10 + U11);
            float term4 = E_c * 0.25f * (U10 + U11 + U20 + U21) - E_d * 0.25f * (U02 + U03 + U12 + U13);
            float advec = 0.5f * (term1 + term2 + term3 + term4);

            float pw = pimm * sws[ty * 66 + tx] + pim0 * sws[ty * 66 + tx + 1]
                     + pipm * sws[(ty + 2) * 66 + tx] + pip0 * sws[(ty + 2) * 66 + tx + 1];
            float trans = -(DA8F * 0.25f * pw * 0.5f * (uzm + r_uzp) * 0.5f) * RDZF;

            float dphi = sps[ty * 66 + tx + 1] - sps[ty * 66 + tx];
            float vc   = sigma[z] * (Pu[z] - Pp[z]) * RDZF;
            float vbar = 0.5f * (sts[ty * 66 + tx] + sts[ty * 66 + tx + 1]) * vc;
            float press = DYF * (dphi * dpi * 0.5f + dpi * 0.5f * CPDF * vbar);

            float lap = r_uzp + uzm + C2v + C0v + ulp + ulm - 6.0f * C1v;
            float diffv = DIFFF * lap;

            if (act) {
                size_t o = (size_t)z * SU + uidx;
                out[o] = (p0da * u0[o] + dt * (advec + trans + press + diffv)) * rp1da;
            }
            uzm = C1v;
        }
        __syncthreads();   // protect buffer before next stage
    }
#undef U1_STAGE
}

// ---------------- k_v1: async DMA single-buffer LDS, UVZS=4, 8 waves/EU ----------------
__global__ __launch_bounds__(256, 8) void k_v1(
        const float* __restrict__ pi, const float* __restrict__ th,
        const float* __restrict__ u, const float* __restrict__ v,
        const float* __restrict__ cy, const float* __restrict__ w,
        const float* __restrict__ phi, const float* __restrict__ pi0,
        const float* __restrict__ v0, const float* __restrict__ pi1,
        const float* __restrict__ sigma, const float* __restrict__ Pu,
        const float* __restrict__ Pp, const float* __restrict__ dtp,
        float dtmul, float* __restrict__ out) {
    // layout (floats): su[0:512) svv[512:1280) sww[1280:1792) stt[1792:2304) spp[2304:2816)
    __shared__ float lds[2816];

    const int tx = threadIdx.x, ty = threadIdx.y;
    const int t = ty * 64 + tx;
    int wgid = xcd_swz(blockIdx.x, NBV);
    int bxi = wgid % 12; int tmp = wgid / 12;
    int by = tmp % 91; int bz = tmp / 91;
    const int X0 = bxi * 64, Yv = by * 4, z0 = bz * UVZB;

    const int x = X0 + tx;
    const int yy = Yv + ty;
    const bool act = (x < NX) && (yy < NYV);
    const int xe = (x < NX) ? x : NX - 1;
    const int yc = (yy < NYV) ? yy : NY;
    const float dt = dtp[0] * dtmul;

    const int xm = wr(xe - 1, NX), xp = wr(xe + 1, NX);
    const int y0 = wr(yc, NY), ymr = wr(yc - 1, NY);
    const int cq0 = (xe == 0) ? NX : (xe - 1);
    const int cq1 = xe, cq2 = xe + 1;
    const int cq3 = (xe + 2 > NX) ? (xe + 2 - NXU) : (xe + 2);

    // ---- z-invariant staging offsets ----
    int o_su[2], o_vv[3];
#pragma unroll
    for (int c = 0; c < 2; ++c) {
        int i = imin(t + c * 256, 334), r = i / 67, j = i - r * 67;
        o_su[c] = wr(Yv - 1 + r, NY) * NXU + wr(X0 - 1 + j, NXU);
    }
#pragma unroll
    for (int c = 0; c < 3; ++c) {
        int i = imin(t + c * 256, 659), s = i / 66, j = i - s * 66;
        o_vv[c] = (wr(Yv - 1 + (s >> 1), NY) + (s & 1)) * NX + wr(X0 - 1 + j, NX);
    }
    int o_ww[2], o_tt[2];
#pragma unroll
    for (int c = 0; c < 2; ++c) {
        int i, r, j;
        i = imin(t + c * 256, 329); r = i / 66; j = i - r * 66;
        o_ww[c] = wr(Yv - 1 + r, NY) * NX + wr(X0 - 1 + j, NX);
        i = imin(t + c * 256, 319); r = i / 64; j = i - r * 64;
        { int cg = X0 + j; if (cg >= NX) cg -= NX;
          o_tt[c] = wr(Yv - 1 + r, NY) * NX + cg; }
    }

    // ---- z-invariant pi coefficients ----
    float Pxv[2][4];
    {
        int rws[2] = {ymr, y0};
        int cqs[4] = {cq0, cq1, cq2, cq3};
#pragma unroll
        for (int r = 0; r < 2; ++r) {
            int rb = rws[r] * NX;
#pragma unroll
            for (int c = 0; c < 4; ++c) {
                int cc = cqs[c];
                Pxv[r][c] = FXC * (pi[rb + wr(cc - 1, NX)] + pi[rb + wr(cc, NX)]);
            }
        }
    }
    float Pgv[4][3];
    {
        int grs[4] = {ymr, ymr + 1, y0, y0 + 1};
        int cls[3] = {xm, xe, xp};
#pragma unroll
        for (int j = 0; j < 4; ++j) {
            int ra = wr(grs[j] - 1, NY) * NX;
            int rb = wr(grs[j], NY) * NX;
            float cj = cy[grs[j]];
#pragma unroll
            for (int c = 0; c < 3; ++c)
                Pgv[j][c] = GXC * (pi[ra + cls[c]] + pi[rb + cls[c]]) * cj;
        }
    }
    const float pvmm = pi[ymr * NX + xm], pv0m = pi[y0 * NX + xm];
    const float pvmp = pi[ymr * NX + xp], pv0p = pi[y0 * NX + xp];
    const float dpi  = pi[y0 * NX + xe] - pi[ymr * NX + xe];
    const float p0da = DA8F * 0.25f * (pi0[ymr * NX + xm] + pi0[y0 * NX + xm] + pi0[ymr * NX + xp] + pi0[y0 * NX + xp]);
    const float p1da = DA8F * 0.25f * (pi1[ymr * NX + xm] + pi1[y0 * NX + xm] + pi1[ymr * NX + xp] + pi1[y0 * NX + xp]);
    const float rp1da = 1.0f / p1da;

    const int vidx = yc * NX + xe;

#define V1_STAGE(zz) { \
    const float* ub_ = u  + (size_t)(zz) * SU; \
    const float* vb_ = v  + (size_t)(zz) * SV; \
    const float* wb_ = w  + (size_t)(zz) * SW; \
    const float* tb_ = th + (size_t)(zz) * SW; \
    const float* pb_ = phi+ (size_t)(zz) * SW; \
    float* Lb = lds + ty * 64; \
    gl_lds(ub_ + o_su[0], Lb);        gl_lds(ub_ + o_su[1], Lb + 256); \
    gl_lds(vb_ + o_vv[0], Lb + 512);  gl_lds(vb_ + o_vv[1], Lb + 768); \
    gl_lds(vb_ + o_vv[2], Lb + 1024); \
    gl_lds(wb_ + o_ww[0], Lb + 1280); gl_lds(wb_ + o_ww[1], Lb + 1536); \
    gl_lds(tb_ + o_tt[0], Lb + 1792); gl_lds(tb_ + o_tt[1], Lb + 2048); \
    gl_lds(pb_ + o_tt[0], Lb + 2304); gl_lds(pb_ + o_tt[1], Lb + 2560); }

    float vzm = (z0 > 0) ? v[(size_t)(z0 - 1) * SV + vidx] : 0.f;
    float vc_r = v[(size_t)z0 * SV + vidx];

    for (int iz = 0; iz < UVZB; ++iz) {
        const int z = z0 + iz;
        V1_STAGE(z);
        float vzp = (z + 1 < NZ) ? v[(size_t)(z + 1) * SV + vidx] : 0.f;
        __syncthreads();

        const float* su  = lds;
        const float* svv = lds + 512;
        const float* sww = lds + 1280;
        const float* stt = lds + 1792;
        const float* spp = lds + 2304;
        {
            const float* pu_m = su + ty * 67;
            const float* pu_0 = su + (ty + 1) * 67;
            float F00 = Pxv[0][0]*pu_m[tx], F01 = Pxv[0][1]*pu_m[tx+1];
            float F02 = Pxv[0][2]*pu_m[tx+2], F03 = Pxv[0][3]*pu_m[tx+3];
            float F10 = Pxv[1][0]*pu_0[tx], F11 = Pxv[1][1]*pu_0[tx+1];
            float F12 = Pxv[1][2]*pu_0[tx+2], F13 = Pxv[1][3]*pu_0[tx+3];

            const float* pv0 = svv + (2 * ty + 0) * 66;
            const float* pv1 = svv + (2 * ty + 1) * 66;
            const float* pv2 = svv + (2 * ty + 2) * 66;
            const float* pv3 = svv + (2 * ty + 3) * 66;
            float V00 = pv0[tx], V01 = pv0[tx+1], V02 = pv0[tx+2];
            float V10 = pv1[tx], V11 = pv1[tx+1], V12 = pv1[tx+2];
            float V20 = pv2[tx], V21 = pv2[tx+1], V22 = pv2[tx+2];
            float V30 = pv3[tx], V31 = pv3[tx+1], V32 = pv3[tx+2];
            float G00 = Pgv[0][0]*V00, G01 = Pgv[0][1]*V01, G02 = Pgv[0][2]*V02;
            float G10 = Pgv[1][0]*V10, G11 = Pgv[1][1]*V11, G12 = Pgv[1][2]*V12;
            float G20 = Pgv[2][0]*V20, G21 = Pgv[2][1]*V21, G22 = Pgv[2][2]*V22;
            float G30 = Pgv[3][0]*V30, G31 = Pgv[3][1]*V31, G32 = Pgv[3][2]*V32;

            float vy_m = (yc < NY) ? V20 : V10;
            float vy_p = (yc < NY) ? V22 : V12;
            float vy_0 = vc_r;

            float Q_p = (F01 + F11 + F03 + F13) * K1;
            float Q_0 = (F00 + F10 + F02 + F12) * K1;
            float term1 = Q_0 * 0.5f * (vy_m + vy_0) - Q_p * 0.5f * (vy_0 + vy_p);

            float R_0 = (G20 + G30 + G22 + G32) * K1;
            float R_m = (G00 + G10 + G02 + G12) * K1;
            float term2 = R_m * 0.5f * (V01 + V11) - R_0 * 0.5f * (V21 + V31);

            float S_a = 0.25f * (G21 + G22 + G31 + G32) + (F11 + F13) * K2v;
            float S_b = 0.25f * (G00 + G01 + G10 + G11) + (F00 + F02) * K2v;
            float T_c = 0.25f * (G20 + G21 + G30 + G31) - (F10 + F12) * K2v;
            float T_d = 0.25f * (G01 + G02 + G11 + G12) - (F01 + F03) * K2v;
            float term3 = S_a * 0.25f * (V21 + V22 + V31 + V32) - S_b * 0.25f * (V00 + V01 + V10 + V11);
            float term4 = T_c * 0.25f * (V20 + V21 + V30 + V31) - T_d * 0.25f * (V01 + V02 + V11 + V12);
            float advec = 0.5f * (term1 + term2 + term3 + term4);

            float pw = pvmm * sww[ty * 66 + tx] + pv0m * sww[(ty + 1) * 66 + tx]
                     + pvmp * sww[ty * 66 + tx + 2] + pv0p * sww[(ty + 1) * 66 + tx + 2];
            float trans = -(DA8F * 0.25f * pw * 0.5f * (vzm + vzp) * 0.5f) * RDZF;

            float dphi = spp[(ty + 1) * 64 + tx] - spp[ty * 64 + tx];
            float vcz  = sigma[z] * (Pu[z] - Pp[z]) * RDZF;
            float vbar = 0.5f * (stt[ty * 64 + tx] + stt[(ty + 1) * 64 + tx]) * vcz;
            float press = DXF * (dphi * dpi * 0.5f + dpi * 0.5f * CPDF * vbar);

            float vlm = (yc > 0) ? V01 : V11;
            float vlp = (yc < NY) ? V31 : V21;
            float lap = vzp + vzm + vlp + vlm + vy_p + vy_m - 6.0f * vc_r;
            float diffv = DIFFF * lap;

            if (act) {
                size_t o = (size_t)z * SV + vidx;
                out[o] = (p0da * v0[o] + dt * (advec + trans + press + diffv)) * rp1da;
            }
            vzm = vc_r; vc_r = vzp;
        }
        __syncthreads();
    }
#undef V1_STAGE
}

extern "C" void kernel_launch(void* const* d_in, const int* in_sizes, int n_in,
                              void* d_out, int out_size, void* d_ws, size_t ws_size,
                              hipStream_t stream) {
    const float* pi    = (const float*)d_in[0];
    const float* theta = (const float*)d_in[1];
    const float* u     = (const float*)d_in[2];
    const float* v     = (const float*)d_in[3];
    const float* w     = (const float*)d_in[4];
    const float* phi   = (const float*)d_in[5];
    const float* Y     = (const float*)d_in[6];
    const float* sigma = (const float*)d_in[8];
    const float* P_    = (const float*)d_in[9];
    const float* P     = (const float*)d_in[10];
    const float* dtp   = (const float*)d_in[12];

    float* out_pi = (float*)d_out;
    float* out_th = out_pi + NY * NX;
    float* out_u  = out_th + NZ * NY * NX;
    float* out_v  = out_u + NZ * NY * NXU;

    float* ws   = (float*)d_ws;
    float* w_pi = ws;
    float* w_th = w_pi + NY * NX;
    float* w_u  = w_th + NZ * NY * NX;
    float* w_v  = w_u + NZ * NY * NXU;
    float* cyt  = w_v + NZ * NYV * NX;

    float* part = out_th;  // consumed by k_pi1_fin before k_theta1 writes out_th

    dim3 blk(256);
    dim3 blk2(64, 4);
    dim3 gpart(3, NY, PZ);
    dim3 gfin(3, NY);

    k_cosy<<<1, 512, 0, stream>>>(Y, cyt);

    // step 1: current = originals, state0 = originals, dt/2
    k_pi1_part<<<gpart, blk, 0, stream>>>(pi, u, v, cyt, part);
    k_pi1_fin<<<gfin, blk, 0, stream>>>(part, pi, dtp, 0.5f, w_pi);
    k_theta1<<<NBT, blk, 0, stream>>>(pi, theta, u, v, cyt, w, pi, theta, w_pi, dtp, 0.5f, w_th);
    k_u1<<<NBU, blk2, 0, stream>>>(pi, theta, u, v, cyt, w, phi, pi, u, w_pi, sigma, P_, P, dtp, 0.5f, w_u);
    k_v1<<<NBV, blk2, 0, stream>>>(pi, theta, u, v, cyt, w, phi, pi, v, w_pi, sigma, P_, P, dtp, 0.5f, w_v);

    // step 2: current = intermediates, state0 = originals, dt
    k_pi1_part<<<gpart, blk, 0, stream>>>(w_pi, w_u, w_v, cyt, part);
    k_pi1_fin<<<gfin, blk, 0, stream>>>(part, pi, dtp, 1.0f, out_pi);
    k_theta1<<<NBT, blk, 0, stream>>>(w_pi, w_th, w_u, w_v, cyt, w, pi, theta, out_pi, dtp, 1.0f, out_th);
    k_u1<<<NBU, blk2, 0, stream>>>(w_pi, w_th, w_u, w_v, cyt, w, phi, pi, u, out_pi, sigma, P_, P, dtp, 1.0f, out_u);
    k_v1<<<NBV, blk2, 0, stream>>>(w_pi, w_th, w_u, w_v, cyt, w, phi, pi, v, out_pi, sigma, P_, P, dtp, 1.0f, out_v);
}

// Round 15
// 591.661 us; speedup vs baseline: 4.1375x; 4.1375x over previous
//
#include <hip/hip_runtime.h>
#include <math.h>

#define NZ 32
#define NY 360
#define NX 720
#define NXU (NX + 1)   // 721
#define NYV (NY + 1)   // 361
#define SU (NY * NXU)
#define SV (NYV * NX)
#define SW (NY * NX)
#define UVZS 8
#define UVZB (NZ / UVZS)   // 4
#define TZS 2
#define TZB (NZ / TZS)     // 16
#define PZ 4
#define PZB (NZ / PZ)
#define NBU (12 * 90 * UVZS)   // 8640
#define NBV (12 * 91 * UVZS)   // 8736
#define NBT (3 * NY * TZS)     // 2160

static constexpr double PI_D = 3.14159265358979323846;
static constexpr double RE_D = 6400000.0;
static constexpr double DX_D = 2.0 * PI_D / NX;
static constexpr double DY_D = PI_D / NY;
static constexpr double DA_D = RE_D * DX_D * (RE_D * DY_D);

constexpr float FXC   = (float)(0.25 * RE_D * DY_D);
constexpr float GXC   = (float)(0.25 * RE_D * DX_D);
constexpr float DAF   = (float)DA_D;
constexpr float DA8F  = (float)(DA_D / 8.0);
constexpr float DYF   = (float)DY_D;
constexpr float DXF   = (float)DX_D;
constexpr float CPDF  = 1004.67f;
constexpr float DIFFF = 1.0e9f;
constexpr float RDZF  = 32.0f;
constexpr float DZF   = 0.03125f;
constexpr float K1    = 0.25f / 12.0f;
constexpr float K2u   = 0.25f / 24.0f;
constexpr float K2v   = 0.5f / 24.0f;

__device__ __forceinline__ int wr(int i, int n) {
    return i < 0 ? i + n : (i >= n ? i - n : i);
}

__device__ __forceinline__ int imin(int a, int b) { return a < b ? a : b; }

__device__ __forceinline__ int xcd_swz(int bid, int nwg) {
    int q = nwg >> 3, r = nwg & 7;
    int xcd = bid & 7, off = bid >> 3;
    return (xcd < r ? xcd * (q + 1) : r * (q + 1) + (xcd - r) * q) + off;
}

// async global->LDS DMA, 4B/lane. LDS dest = wave-uniform base + lane*4.
__device__ __forceinline__ void gl_lds(const float* g, float* l) {
    __builtin_amdgcn_global_load_lds(
        (const __attribute__((address_space(1))) void*)g,
        (__attribute__((address_space(3))) void*)l,
        4, 0, 0);
}

__global__ void k_cosy(const float* __restrict__ Y, float* __restrict__ cy) {
    int t = threadIdx.x;
    if (t < NYV) cy[t] = cosf(Y[t]);
}

__global__ __launch_bounds__(256, 8) void k_pi1_part(
        const float* __restrict__ pi, const float* __restrict__ u,
        const float* __restrict__ v, const float* __restrict__ cy,
        float* __restrict__ part) {
    int x = blockIdx.x * blockDim.x + threadIdx.x;
    int y = blockIdx.y;
    int bz = blockIdx.z;
    if (x >= NX) return;
    int xm = wr(x - 1, NX), xp = wr(x + 1, NX);
    float pc  = pi[y * NX + x];
    float a_m = FXC * (pi[y * NX + xm] + pc);
    float a_p = FXC * (pc + pi[y * NX + xp]);
    float g_lo = GXC * (pi[wr(y - 1, NY) * NX + x] + pc) * cy[y];
    float g_hi = GXC * (pc + pi[wr(y + 1, NY) * NX + x]) * cy[y + 1];
    float acc = 0.f;
    int z0 = bz * PZB;
#pragma unroll
    for (int iz = 0; iz < PZB; ++iz) {
        int z = z0 + iz;
        float fxm = a_m * u[((size_t)z * NY + y) * NXU + x];
        float fxp = a_p * u[((size_t)z * NY + y) * NXU + x + 1];
        float glo = g_lo * v[((size_t)z * NYV + y) * NX + x];
        float ghi = g_hi * v[((size_t)z * NYV + y + 1) * NX + x];
        acc += ((fxp - fxm) + (ghi - glo)) * DZF;
    }
    part[(size_t)bz * SW + y * NX + x] = acc;
}

__global__ __launch_bounds__(256, 8) void k_pi1_fin(
        const float* __restrict__ part, const float* __restrict__ pi0,
        const float* __restrict__ dtp, float dtmul, float* __restrict__ out) {
    int x = blockIdx.x * blockDim.x + threadIdx.x;
    int y = blockIdx.y;
    if (x >= NX) return;
    float dt = dtp[0] * dtmul;
    int i = y * NX + x;
    float s = part[i] + part[SW + i] + part[2 * SW + i] + part[3 * SW + i];
    out[i] = pi0[i] - dt / DAF * s;
}

__global__ __launch_bounds__(256, 4) void k_theta1(
        const float* __restrict__ pi, const float* __restrict__ th,
        const float* __restrict__ u, const float* __restrict__ v,
        const float* __restrict__ cy, const float* __restrict__ w,
        const float* __restrict__ pi0, const float* __restrict__ th0,
        const float* __restrict__ pi1, const float* __restrict__ dtp,
        float dtmul, float* __restrict__ out) {
    int wgid = xcd_swz(blockIdx.x, NBT);
    int bx = wgid % 3; int tmp = wgid / 3;
    int y = tmp % NY; int bz = tmp / NY;
    int x = bx * 256 + threadIdx.x;
    if (x >= NX) return;
    float dt = dtp[0] * dtmul;
    int xm = wr(x - 1, NX), xp = wr(x + 1, NX);
    int ym = wr(y - 1, NY), yp = wr(y + 1, NY);
    float pc  = pi[y * NX + x];
    float a_m = FXC * (pi[y * NX + xm] + pc);
    float a_p = FXC * (pc + pi[y * NX + xp]);
    float g_lo = GXC * (pi[ym * NX + x] + pc) * cy[y];
    float g_hi = GXC * (pc + pi[yp * NX + x]) * cy[y + 1];
    float rp1  = 1.0f / pi1[y * NX + x];
    float c0v  = pi0[y * NX + x] * rp1;
    float cvert = pc * DAF * RDZF;
    float cdt  = dt / DAF * rp1;
    int base = y * NX + x;
    int z0 = bz * TZB;
    float tc  = th[(size_t)z0 * SW + base];
    float tzm = (z0 > 0) ? th[(size_t)(z0 - 1) * SW + base] : 0.f;
#pragma unroll 4
    for (int iz = 0; iz < TZB; ++iz) {
        int z = z0 + iz;
        const float* tb = th + (size_t)z * SW;
        float tzp = (z + 1 < NZ) ? tb[SW + base] : 0.f;
        float t_xm = tb[y * NX + xm], t_xp = tb[y * NX + xp];
        float t_ym = tb[ym * NX + x], t_yp = tb[yp * NX + x];
        float fx0 = a_m * u[((size_t)z * NY + y) * NXU + x];
        float fx1 = a_p * u[((size_t)z * NY + y) * NXU + x + 1];
        float gg0 = g_lo * v[((size_t)z * NYV + y) * NX + x];
        float gg1 = g_hi * v[((size_t)z * NYV + y + 1) * NX + x];
        float adv = (fx1 * 0.5f * (tc + t_xp) - fx0 * 0.5f * (t_xm + tc)
                   + gg1 * 0.5f * (tc + t_yp) - gg0 * 0.5f * (t_ym + tc)) * 0.5f;
        float th0v = th0[(size_t)z * SW + base];
        float vert = cvert * (w[(size_t)z * SW + base] * th0v);
        float lap = tzp + tzm + t_yp + t_ym + t_xp + t_xm - 6.0f * tc;
        out[(size_t)z * SW + base] = c0v * th0v + cdt * (adv + vert + DIFFF * lap);
        tzm = tc; tc = tzp;
    }
}

// ---------------- k_u1: async DMA single-buffer LDS, UVZS=8 ----------------
__global__ __launch_bounds__(256, 4) void k_u1(
        const float* __restrict__ pi, const float* __restrict__ th,
        const float* __restrict__ u, const float* __restrict__ v,
        const float* __restrict__ cy, const float* __restrict__ w,
        const float* __restrict__ phi, const float* __restrict__ pi0,
        const float* __restrict__ u0, const float* __restrict__ pi1,
        const float* __restrict__ sigma, const float* __restrict__ Pu,
        const float* __restrict__ Pp, const float* __restrict__ dtp,
        float dtmul, float* __restrict__ out) {
    // layout (floats): su[0:512) svs[512:1024) sws[1024:1536) sts[1536:2048) sps[2048:2560)
    __shared__ float lds[2560];

    const int tx = threadIdx.x, ty = threadIdx.y;
    const int t = ty * 64 + tx;
    int wgid = xcd_swz(blockIdx.x, NBU);
    int bxi = wgid % 12; int tmp = wgid / 12;
    int by = tmp % 90; int bz = tmp / 90;
    const int X0 = bxi * 64, Y = by * 4, z0 = bz * UVZB;

    const int x = X0 + tx;
    const bool act = (x < NXU);
    const int xe = act ? x : NX;
    const int y = Y + ty;
    const float dt = dtp[0] * dtmul;

    const int x0 = wr(xe, NX), xm = wr(xe - 1, NX);
    const int ym = wr(y - 1, NY), yp = wr(y + 1, NY);
    const int c0 = xm, c1 = xm + 1, c2 = x0, c3 = x0 + 1;

    // ---- z-invariant staging offsets (clamped duplicates in pad region) ----
    int o_su[2], o_sv[2], o_sw[2], o_st[2];
#pragma unroll
    for (int c = 0; c < 2; ++c) {
        int i, r, j;
        i = imin(t + c * 256, 401); r = i / 67; j = i - r * 67;
        o_su[c] = wr(Y - 1 + r, NY) * NXU + wr(X0 - 1 + j, NXU);
        i = imin(t + c * 256, 461); r = i / 66; j = i - r * 66;
        o_sv[c] = wr(Y - 1 + r, NYV) * NX + wr(X0 - 1 + j, NX);
        i = imin(t + c * 256, 395); r = i / 66; j = i - r * 66;
        o_sw[c] = wr(Y - 1 + r, NY) * NX + wr(X0 - 1 + j, NX);
        i = imin(t + c * 256, 263); r = i / 66; j = i - r * 66;
        o_st[c] = (Y + r) * NX + wr(X0 - 1 + j, NX);
    }

    // ---- z-invariant pi coefficients ----
    float Px[3][4];
    {
        int rows3[3] = {ym, y, yp};
        int cols4[4] = {c0, c1, c2, c3};
#pragma unroll
        for (int r = 0; r < 3; ++r) {
            int rb = rows3[r] * NX;
#pragma unroll
            for (int c = 0; c < 4; ++c) {
                int cc = cols4[c];
                Px[r][c] = FXC * (pi[rb + wr(cc - 1, NX)] + pi[rb + wr(cc, NX)]);
            }
        }
    }
    float Pg[4][2];
#pragma unroll
    for (int j = 0; j < 4; ++j) {
        int grow = wr(Y - 1 + ty + j, NYV);
        int ra = wr(grow - 1, NY) * NX;
        int rb = wr(grow, NY) * NX;
        float cj = cy[grow];
        Pg[j][0] = GXC * (pi[ra + xm] + pi[rb + xm]) * cj;
        Pg[j][1] = GXC * (pi[ra + x0] + pi[rb + x0]) * cj;
    }
    const float pimm = pi[ym * NX + xm], pim0 = pi[ym * NX + x0];
    const float pipm = pi[yp * NX + xm], pip0 = pi[yp * NX + x0];
    const float dpi  = pi[y * NX + x0] - pi[y * NX + xm];
    const float p0da = DA8F * 0.25f * (pi0[ym * NX + xm] + pi0[ym * NX + x0] + pi0[yp * NX + xm] + pi0[yp * NX + x0]);
    const float p1da = DA8F * 0.25f * (pi1[ym * NX + xm] + pi1[ym * NX + x0] + pi1[yp * NX + xm] + pi1[yp * NX + x0]);
    const float rp1da = 1.0f / p1da;

    const int uidx = y * NXU + xe;
    const int jc1 = (xe == 0) ? tx : tx + 1;
    const int jc2 = (xe < NX) ? tx + 1 : tx + 2;

#define U1_STAGE(zz) { \
    const float* ub_ = u  + (size_t)(zz) * SU; \
    const float* vb_ = v  + (size_t)(zz) * SV; \
    const float* wb_ = w  + (size_t)(zz) * SW; \
    const float* tb_ = th + (size_t)(zz) * SW; \
    const float* pb_ = phi+ (size_t)(zz) * SW; \
    float* Lb = lds + ty * 64; \
    gl_lds(ub_ + o_su[0], Lb);        gl_lds(ub_ + o_su[1], Lb + 256); \
    gl_lds(vb_ + o_sv[0], Lb + 512);  gl_lds(vb_ + o_sv[1], Lb + 768); \
    gl_lds(wb_ + o_sw[0], Lb + 1024); gl_lds(wb_ + o_sw[1], Lb + 1280); \
    gl_lds(tb_ + o_st[0], Lb + 1536); gl_lds(tb_ + o_st[1], Lb + 1792); \
    gl_lds(pb_ + o_st[0], Lb + 2048); gl_lds(pb_ + o_st[1], Lb + 2304); }

    float uzm = (z0 > 0) ? u[(size_t)(z0 - 1) * SU + uidx] : 0.f;

    for (int iz = 0; iz < UVZB; ++iz) {
        const int z = z0 + iz;
        U1_STAGE(z);                                        // async DMA issue
        const float* ub = u + (size_t)z * SU;               // xe==0 patch + ring
        float r_uzp = (z + 1 < NZ) ? ub[SU + uidx] : 0.f;
        __syncthreads();                                    // drain DMA + join

        const float* su  = lds;
        const float* svs = lds + 512;
        const float* sws = lds + 1024;
        const float* sts = lds + 1536;
        const float* sps = lds + 2048;
        {
            const float* su0 = su + ty * 67;
            const float* su1 = su + (ty + 1) * 67;
            const float* su2 = su + (ty + 2) * 67;
            float U00 = su0[tx], U01 = su0[jc1], U02 = su0[jc2], U03 = su0[jc2 + 1], C0v = su0[tx + 1];
            float U10 = su1[tx], U11 = su1[jc1], U12 = su1[jc2], U13 = su1[jc2 + 1], C1v = su1[tx + 1];
            float U20 = su2[tx], U21 = su2[jc1], U22 = su2[jc2], U23 = su2[jc2 + 1], C2v = su2[tx + 1];
            float ulm = U10;
            float ulp = (xe < NX) ? U13 : U12;
            if (xe == 0) {
                U00 = ub[ym * NXU + (NX - 1)];
                U10 = ub[y  * NXU + (NX - 1)];
                U20 = ub[yp * NXU + (NX - 1)];
            }

            float F00 = Px[0][0]*U00, F01 = Px[0][1]*U01, F02 = Px[0][2]*U02, F03 = Px[0][3]*U03;
            float F10 = Px[1][0]*U10, F11 = Px[1][1]*U11, F12 = Px[1][2]*U12, F13 = Px[1][3]*U13;
            float F20 = Px[2][0]*U20, F21 = Px[2][1]*U21, F22 = Px[2][2]*U22, F23 = Px[2][3]*U23;

            const float* pv0 = svs + (ty + 0) * 66;
            const float* pv1 = svs + (ty + 1) * 66;
            const float* pv2 = svs + (ty + 2) * 66;
            const float* pv3 = svs + (ty + 3) * 66;
            float G00 = Pg[0][0]*pv0[tx], G01 = Pg[0][1]*pv0[tx + 1];
            float G10 = Pg[1][0]*pv1[tx], G11 = Pg[1][1]*pv1[tx + 1];
            float G20 = Pg[2][0]*pv2[tx], G21 = Pg[2][1]*pv2[tx + 1];
            float G30 = Pg[3][0]*pv3[tx], G31 = Pg[3][1]*pv3[tx + 1];

            float B0 = (F02 + F03 + F22 + F23) * K1;
            float Bm = (F00 + F01 + F20 + F21) * K1;
            float term1 = Bm * 0.5f * (U10 + U11) - B0 * 0.5f * (U12 + U13);

            float Cp = (G10 + G11 + G30 + G31) * K1;
            float C0t = (G00 + G01 + G20 + G21) * K1;
            float term2 = C0t * 0.5f * (C0v + C1v) - Cp * 0.5f * (C1v + C2v);

            float D_a = 0.5f * (G11 + G31) + (F12 + F13 + F22 + F23) * K2u;
            float D_b = 0.5f * (G00 + G20) + (F00 + F01 + F10 + F11) * K2u;
            float E_c = 0.5f * (G10 + G30) - (F10 + F11 + F20 + F21) * K2u;
            float E_d = 0.5f * (G01 + G21) - (F02 + F03 + F12 + F13) * K2u;
            float term3 = D_a * 0.25f * (U12 + U13 + U22 + U23) - D_b * 0.25f * (U00 + U01 + U10 + U11);
            float term4 = E_c * 0.25f * (U10 + U11 + U20 + U21) - E_d * 0.25f * (U02 + U03 + U12 + U13);
            float advec = 0.5f * (term1 + term2 + term3 + term4);

            float pw = pimm * sws[ty * 66 + tx] + pim0 * sws[ty * 66 + tx + 1]
                     + pipm * sws[(ty + 2) * 66 + tx] + pip0 * sws[(ty + 2) * 66 + tx + 1];
            float trans = -(DA8F * 0.25f * pw * 0.5f * (uzm + r_uzp) * 0.5f) * RDZF;

            float dphi = sps[ty * 66 + tx + 1] - sps[ty * 66 + tx];
            float vc   = sigma[z] * (Pu[z] - Pp[z]) * RDZF;
            float vbar = 0.5f * (sts[ty * 66 + tx] + sts[ty * 66 + tx + 1]) * vc;
            float press = DYF * (dphi * dpi * 0.5f + dpi * 0.5f * CPDF * vbar);

            float lap = r_uzp + uzm + C2v + C0v + ulp + ulm - 6.0f * C1v;
            float diffv = DIFFF * lap;

            if (act) {
                size_t o = (size_t)z * SU + uidx;
                out[o] = (p0da * u0[o] + dt * (advec + trans + press + diffv)) * rp1da;
            }
            uzm = C1v;
        }
        __syncthreads();   // protect buffer before next stage
    }
#undef U1_STAGE
}

// ---------------- k_v1: async DMA single-buffer LDS, UVZS=8 ----------------
__global__ __launch_bounds__(256, 4) void k_v1(
        const float* __restrict__ pi, const float* __restrict__ th,
        const float* __restrict__ u, const float* __restrict__ v,
        const float* __restrict__ cy, const float* __restrict__ w,
        const float* __restrict__ phi, const float* __restrict__ pi0,
        const float* __restrict__ v0, const float* __restrict__ pi1,
        const float* __restrict__ sigma, const float* __restrict__ Pu,
        const float* __restrict__ Pp, const float* __restrict__ dtp,
        float dtmul, float* __restrict__ out) {
    // layout (floats): su[0:512) svv[512:1280) sww[1280:1792) stt[1792:2304) spp[2304:2816)
    __shared__ float lds[2816];

    const int tx = threadIdx.x, ty = threadIdx.y;
    const int t = ty * 64 + tx;
    int wgid = xcd_swz(blockIdx.x, NBV);
    int bxi = wgid % 12; int tmp = wgid / 12;
    int by = tmp % 91; int bz = tmp / 91;
    const int X0 = bxi * 64, Yv = by * 4, z0 = bz * UVZB;

    const int x = X0 + tx;
    const int yy = Yv + ty;
    const bool act = (x < NX) && (yy < NYV);
    const int xe = (x < NX) ? x : NX - 1;
    const int yc = (yy < NYV) ? yy : NY;
    const float dt = dtp[0] * dtmul;

    const int xm = wr(xe - 1, NX), xp = wr(xe + 1, NX);
    const int y0 = wr(yc, NY), ymr = wr(yc - 1, NY);
    const int cq0 = (xe == 0) ? NX : (xe - 1);
    const int cq1 = xe, cq2 = xe + 1;
    const int cq3 = (xe + 2 > NX) ? (xe + 2 - NXU) : (xe + 2);

    // ---- z-invariant staging offsets ----
    int o_su[2], o_vv[3], o_ww[2], o_tt[2];
#pragma unroll
    for (int c = 0; c < 2; ++c) {
        int i, r, j;
        i = imin(t + c * 256, 334); r = i / 67; j = i - r * 67;
        o_su[c] = wr(Yv - 1 + r, NY) * NXU + wr(X0 - 1 + j, NXU);
        i = imin(t + c * 256, 329); r = i / 66; j = i - r * 66;
        o_ww[c] = wr(Yv - 1 + r, NY) * NX + wr(X0 - 1 + j, NX);
        i = imin(t + c * 256, 319); r = i / 64; j = i - r * 64;
        { int cg = X0 + j; if (cg >= NX) cg -= NX;
          o_tt[c] = wr(Yv - 1 + r, NY) * NX + cg; }
    }
#pragma unroll
    for (int c = 0; c < 3; ++c) {
        int i = imin(t + c * 256, 659), s = i / 66, j = i - s * 66;
        o_vv[c] = (wr(Yv - 1 + (s >> 1), NY) + (s & 1)) * NX + wr(X0 - 1 + j, NX);
    }

    // ---- z-invariant pi coefficients ----
    float Pxv[2][4];
    {
        int rws[2] = {ymr, y0};
        int cqs[4] = {cq0, cq1, cq2, cq3};
#pragma unroll
        for (int r = 0; r < 2; ++r) {
            int rb = rws[r] * NX;
#pragma unroll
            for (int c = 0; c < 4; ++c) {
                int cc = cqs[c];
                Pxv[r][c] = FXC * (pi[rb + wr(cc - 1, NX)] + pi[rb + wr(cc, NX)]);
            }
        }
    }
    float Pgv[4][3];
    {
        int grs[4] = {ymr, ymr + 1, y0, y0 + 1};
        int cls[3] = {xm, xe, xp};
#pragma unroll
        for (int j = 0; j < 4; ++j) {
            int ra = wr(grs[j] - 1, NY) * NX;
            int rb = wr(grs[j], NY) * NX;
            float cj = cy[grs[j]];
#pragma unroll
            for (int c = 0; c < 3; ++c)
                Pgv[j][c] = GXC * (pi[ra + cls[c]] + pi[rb + cls[c]]) * cj;
        }
    }
    const float pvmm = pi[ymr * NX + xm], pv0m = pi[y0 * NX + xm];
    const float pvmp = pi[ymr * NX + xp], pv0p = pi[y0 * NX + xp];
    const float dpi  = pi[y0 * NX + xe] - pi[ymr * NX + xe];
    const float p0da = DA8F * 0.25f * (pi0[ymr * NX + xm] + pi0[y0 * NX + xm] + pi0[ymr * NX + xp] + pi0[y0 * NX + xp]);
    const float p1da = DA8F * 0.25f * (pi1[ymr * NX + xm] + pi1[y0 * NX + xm] + pi1[ymr * NX + xp] + pi1[y0 * NX + xp]);
    const float rp1da = 1.0f / p1da;

    const int vidx = yc * NX + xe;

#define V1_STAGE(zz) { \
    const float* ub_ = u  + (size_t)(zz) * SU; \
    const float* vb_ = v  + (size_t)(zz) * SV; \
    const float* wb_ = w  + (size_t)(zz) * SW; \
    const float* tb_ = th + (size_t)(zz) * SW; \
    const float* pb_ = phi+ (size_t)(zz) * SW; \
    float* Lb = lds + ty * 64; \
    gl_lds(ub_ + o_su[0], Lb);        gl_lds(ub_ + o_su[1], Lb + 256); \
    gl_lds(vb_ + o_vv[0], Lb + 512);  gl_lds(vb_ + o_vv[1], Lb + 768); \
    gl_lds(vb_ + o_vv[2], Lb + 1024); \
    gl_lds(wb_ + o_ww[0], Lb + 1280); gl_lds(wb_ + o_ww[1], Lb + 1536); \
    gl_lds(tb_ + o_tt[0], Lb + 1792); gl_lds(tb_ + o_tt[1], Lb + 2048); \
    gl_lds(pb_ + o_tt[0], Lb + 2304); gl_lds(pb_ + o_tt[1], Lb + 2560); }

    float vzm = (z0 > 0) ? v[(size_t)(z0 - 1) * SV + vidx] : 0.f;
    float vc_r = v[(size_t)z0 * SV + vidx];

    for (int iz = 0; iz < UVZB; ++iz) {
        const int z = z0 + iz;
        V1_STAGE(z);
        float vzp = (z + 1 < NZ) ? v[(size_t)(z + 1) * SV + vidx] : 0.f;
        __syncthreads();

        const float* su  = lds;
        const float* svv = lds + 512;
        const float* sww = lds + 1280;
        const float* stt = lds + 1792;
        const float* spp = lds + 2304;
        {
            const float* pu_m = su + ty * 67;
            const float* pu_0 = su + (ty + 1) * 67;
            float F00 = Pxv[0][0]*pu_m[tx], F01 = Pxv[0][1]*pu_m[tx+1];
            float F02 = Pxv[0][2]*pu_m[tx+2], F03 = Pxv[0][3]*pu_m[tx+3];
            float F10 = Pxv[1][0]*pu_0[tx], F11 = Pxv[1][1]*pu_0[tx+1];
            float F12 = Pxv[1][2]*pu_0[tx+2], F13 = Pxv[1][3]*pu_0[tx+3];

            const float* pv0 = svv + (2 * ty + 0) * 66;
            const float* pv1 = svv + (2 * ty + 1) * 66;
            const float* pv2 = svv + (2 * ty + 2) * 66;
            const float* pv3 = svv + (2 * ty + 3) * 66;
            float V00 = pv0[tx], V01 = pv0[tx+1], V02 = pv0[tx+2];
            float V10 = pv1[tx], V11 = pv1[tx+1], V12 = pv1[tx+2];
            float V20 = pv2[tx], V21 = pv2[tx+1], V22 = pv2[tx+2];
            float V30 = pv3[tx], V31 = pv3[tx+1], V32 = pv3[tx+2];
            float G00 = Pgv[0][0]*V00, G01 = Pgv[0][1]*V01, G02 = Pgv[0][2]*V02;
            float G10 = Pgv[1][0]*V10, G11 = Pgv[1][1]*V11, G12 = Pgv[1][2]*V12;
            float G20 = Pgv[2][0]*V20, G21 = Pgv[2][1]*V21, G22 = Pgv[2][2]*V22;
            float G30 = Pgv[3][0]*V30, G31 = Pgv[3][1]*V31, G32 = Pgv[3][2]*V32;

            float vy_m = (yc < NY) ? V20 : V10;
            float vy_p = (yc < NY) ? V22 : V12;
            float vy_0 = vc_r;

            float Q_p = (F01 + F11 + F03 + F13) * K1;
            float Q_0 = (F00 + F10 + F02 + F12) * K1;
            float term1 = Q_0 * 0.5f * (vy_m + vy_0) - Q_p * 0.5f * (vy_0 + vy_p);

            float R_0 = (G20 + G30 + G22 + G32) * K1;
            float R_m = (G00 + G10 + G02 + G12) * K1;
            float term2 = R_m * 0.5f * (V01 + V11) - R_0 * 0.5f * (V21 + V31);

            float S_a = 0.25f * (G21 + G22 + G31 + G32) + (F11 + F13) * K2v;
            float S_b = 0.25f * (G00 + G01 + G10 + G11) + (F00 + F02) * K2v;
            float T_c = 0.25f * (G20 + G21 + G30 + G31) - (F10 + F12) * K2v;
            float T_d = 0.25f * (G01 + G02 + G11 + G12) - (F01 + F03) * K2v;
            float term3 = S_a * 0.25f * (V21 + V22 + V31 + V32) - S_b * 0.25f * (V00 + V01 + V10 + V11);
            float term4 = T_c * 0.25f * (V20 + V21 + V30 + V31) - T_d * 0.25f * (V01 + V02 + V11 + V12);
            float advec = 0.5f * (term1 + term2 + term3 + term4);

            float pw = pvmm * sww[ty * 66 + tx] + pv0m * sww[(ty + 1) * 66 + tx]
                     + pvmp * sww[ty * 66 + tx + 2] + pv0p * sww[(ty + 1) * 66 + tx + 2];
            float trans = -(DA8F * 0.25f * pw * 0.5f * (vzm + vzp) * 0.5f) * RDZF;

            float dphi = spp[(ty + 1) * 64 + tx] - spp[ty * 64 + tx];
            float vcz  = sigma[z] * (Pu[z] - Pp[z]) * RDZF;
            float vbar = 0.5f * (stt[ty * 64 + tx] + stt[(ty + 1) * 64 + tx]) * vcz;
            float press = DXF * (dphi * dpi * 0.5f + dpi * 0.5f * CPDF * vbar);

            float vlm = (yc > 0) ? V01 : V11;
            float vlp = (yc < NY) ? V31 : V21;
            float lap = vzp + vzm + vlp + vlm + vy_p + vy_m - 6.0f * vc_r;
            float diffv = DIFFF * lap;

            if (act) {
                size_t o = (size_t)z * SV + vidx;
                out[o] = (p0da * v0[o] + dt * (advec + trans + press + diffv)) * rp1da;
            }
            vzm = vc_r; vc_r = vzp;
        }
        __syncthreads();
    }
#undef V1_STAGE
}

extern "C" void kernel_launch(void* const* d_in, const int* in_sizes, int n_in,
                              void* d_out, int out_size, void* d_ws, size_t ws_size,
                              hipStream_t stream) {
    const float* pi    = (const float*)d_in[0];
    const float* theta = (const float*)d_in[1];
    const float* u     = (const float*)d_in[2];
    const float* v     = (const float*)d_in[3];
    const float* w     = (const float*)d_in[4];
    const float* phi   = (const float*)d_in[5];
    const float* Y     = (const float*)d_in[6];
    const float* sigma = (const float*)d_in[8];
    const float* P_    = (const float*)d_in[9];
    const float* P     = (const float*)d_in[10];
    const float* dtp   = (const float*)d_in[12];

    float* out_pi = (float*)d_out;
    float* out_th = out_pi + NY * NX;
    float* out_u  = out_th + NZ * NY * NX;
    float* out_v  = out_u + NZ * NY * NXU;

    float* ws   = (float*)d_ws;
    float* w_pi = ws;
    float* w_th = w_pi + NY * NX;
    float* w_u  = w_th + NZ * NY * NX;
    float* w_v  = w_u + NZ * NY * NXU;
    float* cyt  = w_v + NZ * NYV * NX;

    float* part = out_th;  // consumed by k_pi1_fin before k_theta1 writes out_th

    dim3 blk(256);
    dim3 blk2(64, 4);
    dim3 gpart(3, NY, PZ);
    dim3 gfin(3, NY);

    k_cosy<<<1, 512, 0, stream>>>(Y, cyt);

    // step 1: current = originals, state0 = originals, dt/2
    k_pi1_part<<<gpart, blk, 0, stream>>>(pi, u, v, cyt, part);
    k_pi1_fin<<<gfin, blk, 0, stream>>>(part, pi, dtp, 0.5f, w_pi);
    k_theta1<<<NBT, blk, 0, stream>>>(pi, theta, u, v, cyt, w, pi, theta, w_pi, dtp, 0.5f, w_th);
    k_u1<<<NBU, blk2, 0, stream>>>(pi, theta, u, v, cyt, w, phi, pi, u, w_pi, sigma, P_, P, dtp, 0.5f, w_u);
    k_v1<<<NBV, blk2, 0, stream>>>(pi, theta, u, v, cyt, w, phi, pi, v, w_pi, sigma, P_, P, dtp, 0.5f, w_v);

    // step 2: current = intermediates, state0 = originals, dt
    k_pi1_part<<<gpart, blk, 0, stream>>>(w_pi, w_u, w_v, cyt, part);
    k_pi1_fin<<<gfin, blk, 0, stream>>>(part, pi, dtp, 1.0f, out_pi);
    k_theta1<<<NBT, blk, 0, stream>>>(w_pi, w_th, w_u, w_v, cyt, w, pi, theta, out_pi, dtp, 1.0f, out_th);
    k_u1<<<NBU, blk2, 0, stream>>>(w_pi, w_th, w_u, w_v, cyt, w, phi, pi, u, out_pi, sigma, P_, P, dtp, 1.0f, out_u);
    k_v1<<<NBV, blk2, 0, stream>>>(w_pi, w_th, w_u, w_v, cyt, w, phi, pi, v, out_pi, sigma, P_, P, dtp, 1.0f, out_v);
}

// Round 16
// 547.164 us; speedup vs baseline: 4.4739x; 1.0813x over previous
//
#include <hip/hip_runtime.h>
#include <math.h>

#define NZ 32
#define NY 360
#define NX 720
#define NXU (NX + 1)   // 721
#define NYV (NY + 1)   // 361
#define SU (NY * NXU)
#define SV (NYV * NX)
#define SW (NY * NX)
#define UVZS 4
#define UVZB (NZ / UVZS)   // 8
#define TZS 2
#define TZB (NZ / TZS)     // 16
#define PZ 4
#define PZB (NZ / PZ)
#define NBU (12 * 90 * UVZS)   // 4320
#define NBV (12 * 91 * UVZS)   // 4368
#define NBT (3 * NY * TZS)     // 2160

static constexpr double PI_D = 3.14159265358979323846;
static constexpr double RE_D = 6400000.0;
static constexpr double DX_D = 2.0 * PI_D / NX;
static constexpr double DY_D = PI_D / NY;
static constexpr double DA_D = RE_D * DX_D * (RE_D * DY_D);

constexpr float FXC   = (float)(0.25 * RE_D * DY_D);
constexpr float GXC   = (float)(0.25 * RE_D * DX_D);
constexpr float DAF   = (float)DA_D;
constexpr float DA8F  = (float)(DA_D / 8.0);
constexpr float DYF   = (float)DY_D;
constexpr float DXF   = (float)DX_D;
constexpr float CPDF  = 1004.67f;
constexpr float DIFFF = 1.0e9f;
constexpr float RDZF  = 32.0f;
constexpr float DZF   = 0.03125f;
constexpr float K1    = 0.25f / 12.0f;
constexpr float K2u   = 0.25f / 24.0f;
constexpr float K2v   = 0.5f / 24.0f;

__device__ __forceinline__ int wr(int i, int n) {
    return i < 0 ? i + n : (i >= n ? i - n : i);
}

__device__ __forceinline__ int imin(int a, int b) { return a < b ? a : b; }

__device__ __forceinline__ int xcd_swz(int bid, int nwg) {
    int q = nwg >> 3, r = nwg & 7;
    int xcd = bid & 7, off = bid >> 3;
    return (xcd < r ? xcd * (q + 1) : r * (q + 1) + (xcd - r) * q) + off;
}

// async global->LDS DMA, 4B/lane. LDS dest = wave-uniform base + lane*4.
__device__ __forceinline__ void gl_lds(const float* g, float* l) {
    __builtin_amdgcn_global_load_lds(
        (const __attribute__((address_space(1))) void*)g,
        (__attribute__((address_space(3))) void*)l,
        4, 0, 0);
}

__global__ void k_cosy(const float* __restrict__ Y, float* __restrict__ cy) {
    int t = threadIdx.x;
    if (t < NYV) cy[t] = cosf(Y[t]);
}

__global__ __launch_bounds__(256, 8) void k_pi1_part(
        const float* __restrict__ pi, const float* __restrict__ u,
        const float* __restrict__ v, const float* __restrict__ cy,
        float* __restrict__ part) {
    int x = blockIdx.x * blockDim.x + threadIdx.x;
    int y = blockIdx.y;
    int bz = blockIdx.z;
    if (x >= NX) return;
    int xm = wr(x - 1, NX), xp = wr(x + 1, NX);
    float pc  = pi[y * NX + x];
    float a_m = FXC * (pi[y * NX + xm] + pc);
    float a_p = FXC * (pc + pi[y * NX + xp]);
    float g_lo = GXC * (pi[wr(y - 1, NY) * NX + x] + pc) * cy[y];
    float g_hi = GXC * (pc + pi[wr(y + 1, NY) * NX + x]) * cy[y + 1];
    float acc = 0.f;
    int z0 = bz * PZB;
#pragma unroll
    for (int iz = 0; iz < PZB; ++iz) {
        int z = z0 + iz;
        float fxm = a_m * u[((size_t)z * NY + y) * NXU + x];
        float fxp = a_p * u[((size_t)z * NY + y) * NXU + x + 1];
        float glo = g_lo * v[((size_t)z * NYV + y) * NX + x];
        float ghi = g_hi * v[((size_t)z * NYV + y + 1) * NX + x];
        acc += ((fxp - fxm) + (ghi - glo)) * DZF;
    }
    part[(size_t)bz * SW + y * NX + x] = acc;
}

__global__ __launch_bounds__(256, 8) void k_pi1_fin(
        const float* __restrict__ part, const float* __restrict__ pi0,
        const float* __restrict__ dtp, float dtmul, float* __restrict__ out) {
    int x = blockIdx.x * blockDim.x + threadIdx.x;
    int y = blockIdx.y;
    if (x >= NX) return;
    float dt = dtp[0] * dtmul;
    int i = y * NX + x;
    float s = part[i] + part[SW + i] + part[2 * SW + i] + part[3 * SW + i];
    out[i] = pi0[i] - dt / DAF * s;
}

__global__ __launch_bounds__(256, 4) void k_theta1(
        const float* __restrict__ pi, const float* __restrict__ th,
        const float* __restrict__ u, const float* __restrict__ v,
        const float* __restrict__ cy, const float* __restrict__ w,
        const float* __restrict__ pi0, const float* __restrict__ th0,
        const float* __restrict__ pi1, const float* __restrict__ dtp,
        float dtmul, float* __restrict__ out) {
    int wgid = xcd_swz(blockIdx.x, NBT);
    int bx = wgid % 3; int tmp = wgid / 3;
    int y = tmp % NY; int bz = tmp / NY;
    int x = bx * 256 + threadIdx.x;
    if (x >= NX) return;
    float dt = dtp[0] * dtmul;
    int xm = wr(x - 1, NX), xp = wr(x + 1, NX);
    int ym = wr(y - 1, NY), yp = wr(y + 1, NY);
    float pc  = pi[y * NX + x];
    float a_m = FXC * (pi[y * NX + xm] + pc);
    float a_p = FXC * (pc + pi[y * NX + xp]);
    float g_lo = GXC * (pi[ym * NX + x] + pc) * cy[y];
    float g_hi = GXC * (pc + pi[yp * NX + x]) * cy[y + 1];
    float rp1  = 1.0f / pi1[y * NX + x];
    float c0v  = pi0[y * NX + x] * rp1;
    float cvert = pc * DAF * RDZF;
    float cdt  = dt / DAF * rp1;
    int base = y * NX + x;
    int z0 = bz * TZB;
    float tc  = th[(size_t)z0 * SW + base];
    float tzm = (z0 > 0) ? th[(size_t)(z0 - 1) * SW + base] : 0.f;
#pragma unroll 4
    for (int iz = 0; iz < TZB; ++iz) {
        int z = z0 + iz;
        const float* tb = th + (size_t)z * SW;
        float tzp = (z + 1 < NZ) ? tb[SW + base] : 0.f;
        float t_xm = tb[y * NX + xm], t_xp = tb[y * NX + xp];
        float t_ym = tb[ym * NX + x], t_yp = tb[yp * NX + x];
        float fx0 = a_m * u[((size_t)z * NY + y) * NXU + x];
        float fx1 = a_p * u[((size_t)z * NY + y) * NXU + x + 1];
        float gg0 = g_lo * v[((size_t)z * NYV + y) * NX + x];
        float gg1 = g_hi * v[((size_t)z * NYV + y + 1) * NX + x];
        float adv = (fx1 * 0.5f * (tc + t_xp) - fx0 * 0.5f * (t_xm + tc)
                   + gg1 * 0.5f * (tc + t_yp) - gg0 * 0.5f * (t_ym + tc)) * 0.5f;
        float th0v = th0[(size_t)z * SW + base];
        float vert = cvert * (w[(size_t)z * SW + base] * th0v);
        float lap = tzp + tzm + t_yp + t_ym + t_xp + t_xm - 6.0f * tc;
        out[(size_t)z * SW + base] = c0v * th0v + cdt * (adv + vert + DIFFF * lap);
        tzm = tc; tc = tzp;
    }
}

// ---------------- k_u1: async DMA single-buffer LDS, UVZS=4 ----------------
__global__ __launch_bounds__(256, 4) void k_u1(
        const float* __restrict__ pi, const float* __restrict__ th,
        const float* __restrict__ u, const float* __restrict__ v,
        const float* __restrict__ cy, const float* __restrict__ w,
        const float* __restrict__ phi, const float* __restrict__ pi0,
        const float* __restrict__ u0, const float* __restrict__ pi1,
        const float* __restrict__ sigma, const float* __restrict__ Pu,
        const float* __restrict__ Pp, const float* __restrict__ dtp,
        float dtmul, float* __restrict__ out) {
    // layout (floats): su[0:512) svs[512:1024) sws[1024:1536) sts[1536:2048) sps[2048:2560)
    __shared__ float lds[2560];

    const int tx = threadIdx.x, ty = threadIdx.y;
    const int t = ty * 64 + tx;
    int wgid = xcd_swz(blockIdx.x, NBU);
    int bxi = wgid % 12; int tmp = wgid / 12;
    int by = tmp % 90; int bz = tmp / 90;
    const int X0 = bxi * 64, Y = by * 4, z0 = bz * UVZB;

    const int x = X0 + tx;
    const bool act = (x < NXU);
    const int xe = act ? x : NX;
    const int y = Y + ty;
    const float dt = dtp[0] * dtmul;

    const int x0 = wr(xe, NX), xm = wr(xe - 1, NX);
    const int ym = wr(y - 1, NY), yp = wr(y + 1, NY);
    const int c0 = xm, c1 = xm + 1, c2 = x0, c3 = x0 + 1;

    // ---- z-invariant staging offsets (clamped duplicates in pad region) ----
    int o_su[2], o_sv[2], o_sw[2], o_st[2];
#pragma unroll
    for (int c = 0; c < 2; ++c) {
        int i, r, j;
        i = imin(t + c * 256, 401); r = i / 67; j = i - r * 67;
        o_su[c] = wr(Y - 1 + r, NY) * NXU + wr(X0 - 1 + j, NXU);
        i = imin(t + c * 256, 461); r = i / 66; j = i - r * 66;
        o_sv[c] = wr(Y - 1 + r, NYV) * NX + wr(X0 - 1 + j, NX);
        i = imin(t + c * 256, 395); r = i / 66; j = i - r * 66;
        o_sw[c] = wr(Y - 1 + r, NY) * NX + wr(X0 - 1 + j, NX);
        i = imin(t + c * 256, 263); r = i / 66; j = i - r * 66;
        o_st[c] = (Y + r) * NX + wr(X0 - 1 + j, NX);
    }

    // ---- z-invariant pi coefficients ----
    float Px[3][4];
    {
        int rows3[3] = {ym, y, yp};
        int cols4[4] = {c0, c1, c2, c3};
#pragma unroll
        for (int r = 0; r < 3; ++r) {
            int rb = rows3[r] * NX;
#pragma unroll
            for (int c = 0; c < 4; ++c) {
                int cc = cols4[c];
                Px[r][c] = FXC * (pi[rb + wr(cc - 1, NX)] + pi[rb + wr(cc, NX)]);
            }
        }
    }
    float Pg[4][2];
#pragma unroll
    for (int j = 0; j < 4; ++j) {
        int grow = wr(Y - 1 + ty + j, NYV);
        int ra = wr(grow - 1, NY) * NX;
        int rb = wr(grow, NY) * NX;
        float cj = cy[grow];
        Pg[j][0] = GXC * (pi[ra + xm] + pi[rb + xm]) * cj;
        Pg[j][1] = GXC * (pi[ra + x0] + pi[rb + x0]) * cj;
    }
    const float pimm = pi[ym * NX + xm], pim0 = pi[ym * NX + x0];
    const float pipm = pi[yp * NX + xm], pip0 = pi[yp * NX + x0];
    const float dpi  = pi[y * NX + x0] - pi[y * NX + xm];
    const float p0da = DA8F * 0.25f * (pi0[ym * NX + xm] + pi0[ym * NX + x0] + pi0[yp * NX + xm] + pi0[yp * NX + x0]);
    const float p1da = DA8F * 0.25f * (pi1[ym * NX + xm] + pi1[ym * NX + x0] + pi1[yp * NX + xm] + pi1[yp * NX + x0]);
    const float rp1da = 1.0f / p1da;

    const int uidx = y * NXU + xe;
    const int jc1 = (xe == 0) ? tx : tx + 1;
    const int jc2 = (xe < NX) ? tx + 1 : tx + 2;

#define U1_STAGE(zz) { \
    const float* ub_ = u  + (size_t)(zz) * SU; \
    const float* vb_ = v  + (size_t)(zz) * SV; \
    const float* wb_ = w  + (size_t)(zz) * SW; \
    const float* tb_ = th + (size_t)(zz) * SW; \
    const float* pb_ = phi+ (size_t)(zz) * SW; \
    float* Lb = lds + ty * 64; \
    gl_lds(ub_ + o_su[0], Lb);        gl_lds(ub_ + o_su[1], Lb + 256); \
    gl_lds(vb_ + o_sv[0], Lb + 512);  gl_lds(vb_ + o_sv[1], Lb + 768); \
    gl_lds(wb_ + o_sw[0], Lb + 1024); gl_lds(wb_ + o_sw[1], Lb + 1280); \
    gl_lds(tb_ + o_st[0], Lb + 1536); gl_lds(tb_ + o_st[1], Lb + 1792); \
    gl_lds(pb_ + o_st[0], Lb + 2048); gl_lds(pb_ + o_st[1], Lb + 2304); }

    float uzm = (z0 > 0) ? u[(size_t)(z0 - 1) * SU + uidx] : 0.f;

    for (int iz = 0; iz < UVZB; ++iz) {
        const int z = z0 + iz;
        U1_STAGE(z);                                        // async DMA issue
        const float* ub = u + (size_t)z * SU;               // xe==0 patch + ring
        float r_uzp = (z + 1 < NZ) ? ub[SU + uidx] : 0.f;
        __syncthreads();                                    // drain DMA + join

        const float* su  = lds;
        const float* svs = lds + 512;
        const float* sws = lds + 1024;
        const float* sts = lds + 1536;
        const float* sps = lds + 2048;
        {
            const float* su0 = su + ty * 67;
            const float* su1 = su + (ty + 1) * 67;
            const float* su2 = su + (ty + 2) * 67;
            float U00 = su0[tx], U01 = su0[jc1], U02 = su0[jc2], U03 = su0[jc2 + 1], C0v = su0[tx + 1];
            float U10 = su1[tx], U11 = su1[jc1], U12 = su1[jc2], U13 = su1[jc2 + 1], C1v = su1[tx + 1];
            float U20 = su2[tx], U21 = su2[jc1], U22 = su2[jc2], U23 = su2[jc2 + 1], C2v = su2[tx + 1];
            float ulm = U10;
            float ulp = (xe < NX) ? U13 : U12;
            if (xe == 0) {
                U00 = ub[ym * NXU + (NX - 1)];
                U10 = ub[y  * NXU + (NX - 1)];
                U20 = ub[yp * NXU + (NX - 1)];
            }

            float F00 = Px[0][0]*U00, F01 = Px[0][1]*U01, F02 = Px[0][2]*U02, F03 = Px[0][3]*U03;
            float F10 = Px[1][0]*U10, F11 = Px[1][1]*U11, F12 = Px[1][2]*U12, F13 = Px[1][3]*U13;
            float F20 = Px[2][0]*U20, F21 = Px[2][1]*U21, F22 = Px[2][2]*U22, F23 = Px[2][3]*U23;

            const float* pv0 = svs + (ty + 0) * 66;
            const float* pv1 = svs + (ty + 1) * 66;
            const float* pv2 = svs + (ty + 2) * 66;
            const float* pv3 = svs + (ty + 3) * 66;
            float G00 = Pg[0][0]*pv0[tx], G01 = Pg[0][1]*pv0[tx + 1];
            float G10 = Pg[1][0]*pv1[tx], G11 = Pg[1][1]*pv1[tx + 1];
            float G20 = Pg[2][0]*pv2[tx], G21 = Pg[2][1]*pv2[tx + 1];
            float G30 = Pg[3][0]*pv3[tx], G31 = Pg[3][1]*pv3[tx + 1];

            float B0 = (F02 + F03 + F22 + F23) * K1;
            float Bm = (F00 + F01 + F20 + F21) * K1;
            float term1 = Bm * 0.5f * (U10 + U11) - B0 * 0.5f * (U12 + U13);

            float Cp = (G10 + G11 + G30 + G31) * K1;
            float C0t = (G00 + G01 + G20 + G21) * K1;
            float term2 = C0t * 0.5f * (C0v + C1v) - Cp * 0.5f * (C1v + C2v);

            float D_a = 0.5f * (G11 + G31) + (F12 + F13 + F22 + F23) * K2u;
            float D_b = 0.5f * (G00 + G20) + (F00 + F01 + F10 + F11) * K2u;
            float E_c = 0.5f * (G10 + G30) - (F10 + F11 + F20 + F21) * K2u;
            float E_d = 0.5f * (G01 + G21) - (F02 + F03 + F12 + F13) * K2u;
            float term3 = D_a * 0.25f * (U12 + U13 + U22 + U23) - D_b * 0.25f * (U00 + U01 + U10 + U11);
            float term4 = E_c * 0.25f * (U10 + U11 + U20 + U21) - E_d * 0.25f * (U02 + U03 + U12 + U13);
            float advec = 0.5f * (term1 + term2 + term3 + term4);

            float pw = pimm * sws[ty * 66 + tx] + pim0 * sws[ty * 66 + tx + 1]
                     + pipm * sws[(ty + 2) * 66 + tx] + pip0 * sws[(ty + 2) * 66 + tx + 1];
            float trans = -(DA8F * 0.25f * pw * 0.5f * (uzm + r_uzp) * 0.5f) * RDZF;

            float dphi = sps[ty * 66 + tx + 1] - sps[ty * 66 + tx];
            float vc   = sigma[z] * (Pu[z] - Pp[z]) * RDZF;
            float vbar = 0.5f * (sts[ty * 66 + tx] + sts[ty * 66 + tx + 1]) * vc;
            float press = DYF * (dphi * dpi * 0.5f + dpi * 0.5f * CPDF * vbar);

            float lap = r_uzp + uzm + C2v + C0v + ulp + ulm - 6.0f * C1v;
            float diffv = DIFFF * lap;

            if (act) {
                size_t o = (size_t)z * SU + uidx;
                out[o] = (p0da * u0[o] + dt * (advec + trans + press + diffv)) * rp1da;
            }
            uzm = C1v;
        }
        __syncthreads();   // protect buffer before next stage
    }
#undef U1_STAGE
}

// ---------------- k_v1: async DMA single-buffer LDS, UVZS=4 ----------------
__global__ __launch_bounds__(256, 4) void k_v1(
        const float* __restrict__ pi, const float* __restrict__ th,
        const float* __restrict__ u, const float* __restrict__ v,
        const float* __restrict__ cy, const float* __restrict__ w,
        const float* __restrict__ phi, const float* __restrict__ pi0,
        const float* __restrict__ v0, const float* __restrict__ pi1,
        const float* __restrict__ sigma, const float* __restrict__ Pu,
        const float* __restrict__ Pp, const float* __restrict__ dtp,
        float dtmul, float* __restrict__ out) {
    // layout (floats): su[0:512) svv[512:1280) sww[1280:1792) stt[1792:2304) spp[2304:2816)
    __shared__ float lds[2816];

    const int tx = threadIdx.x, ty = threadIdx.y;
    const int t = ty * 64 + tx;
    int wgid = xcd_swz(blockIdx.x, NBV);
    int bxi = wgid % 12; int tmp = wgid / 12;
    int by = tmp % 91; int bz = tmp / 91;
    const int X0 = bxi * 64, Yv = by * 4, z0 = bz * UVZB;

    const int x = X0 + tx;
    const int yy = Yv + ty;
    const bool act = (x < NX) && (yy < NYV);
    const int xe = (x < NX) ? x : NX - 1;
    const int yc = (yy < NYV) ? yy : NY;
    const float dt = dtp[0] * dtmul;

    const int xm = wr(xe - 1, NX), xp = wr(xe + 1, NX);
    const int y0 = wr(yc, NY), ymr = wr(yc - 1, NY);
    const int cq0 = (xe == 0) ? NX : (xe - 1);
    const int cq1 = xe, cq2 = xe + 1;
    const int cq3 = (xe + 2 > NX) ? (xe + 2 - NXU) : (xe + 2);

    // ---- z-invariant staging offsets ----
    int o_su[2], o_vv[3], o_ww[2], o_tt[2];
#pragma unroll
    for (int c = 0; c < 2; ++c) {
        int i, r, j;
        i = imin(t + c * 256, 334); r = i / 67; j = i - r * 67;
        o_su[c] = wr(Yv - 1 + r, NY) * NXU + wr(X0 - 1 + j, NXU);
        i = imin(t + c * 256, 329); r = i / 66; j = i - r * 66;
        o_ww[c] = wr(Yv - 1 + r, NY) * NX + wr(X0 - 1 + j, NX);
        i = imin(t + c * 256, 319); r = i / 64; j = i - r * 64;
        { int cg = X0 + j; if (cg >= NX) cg -= NX;
          o_tt[c] = wr(Yv - 1 + r, NY) * NX + cg; }
    }
#pragma unroll
    for (int c = 0; c < 3; ++c) {
        int i = imin(t + c * 256, 659), s = i / 66, j = i - s * 66;
        o_vv[c] = (wr(Yv - 1 + (s >> 1), NY) + (s & 1)) * NX + wr(X0 - 1 + j, NX);
    }

    // ---- z-invariant pi coefficients ----
    float Pxv[2][4];
    {
        int rws[2] = {ymr, y0};
        int cqs[4] = {cq0, cq1, cq2, cq3};
#pragma unroll
        for (int r = 0; r < 2; ++r) {
            int rb = rws[r] * NX;
#pragma unroll
            for (int c = 0; c < 4; ++c) {
                int cc = cqs[c];
                Pxv[r][c] = FXC * (pi[rb + wr(cc - 1, NX)] + pi[rb + wr(cc, NX)]);
            }
        }
    }
    float Pgv[4][3];
    {
        int grs[4] = {ymr, ymr + 1, y0, y0 + 1};
        int cls[3] = {xm, xe, xp};
#pragma unroll
        for (int j = 0; j < 4; ++j) {
            int ra = wr(grs[j] - 1, NY) * NX;
            int rb = wr(grs[j], NY) * NX;
            float cj = cy[grs[j]];
#pragma unroll
            for (int c = 0; c < 3; ++c)
                Pgv[j][c] = GXC * (pi[ra + cls[c]] + pi[rb + cls[c]]) * cj;
        }
    }
    const float pvmm = pi[ymr * NX + xm], pv0m = pi[y0 * NX + xm];
    const float pvmp = pi[ymr * NX + xp], pv0p = pi[y0 * NX + xp];
    const float dpi  = pi[y0 * NX + xe] - pi[ymr * NX + xe];
    const float p0da = DA8F * 0.25f * (pi0[ymr * NX + xm] + pi0[y0 * NX + xm] + pi0[ymr * NX + xp] + pi0[y0 * NX + xp]);
    const float p1da = DA8F * 0.25f * (pi1[ymr * NX + xm] + pi1[y0 * NX + xm] + pi1[ymr * NX + xp] + pi1[y0 * NX + xp]);
    const float rp1da = 1.0f / p1da;

    const int vidx = yc * NX + xe;

#define V1_STAGE(zz) { \
    const float* ub_ = u  + (size_t)(zz) * SU; \
    const float* vb_ = v  + (size_t)(zz) * SV; \
    const float* wb_ = w  + (size_t)(zz) * SW; \
    const float* tb_ = th + (size_t)(zz) * SW; \
    const float* pb_ = phi+ (size_t)(zz) * SW; \
    float* Lb = lds + ty * 64; \
    gl_lds(ub_ + o_su[0], Lb);        gl_lds(ub_ + o_su[1], Lb + 256); \
    gl_lds(vb_ + o_vv[0], Lb + 512);  gl_lds(vb_ + o_vv[1], Lb + 768); \
    gl_lds(vb_ + o_vv[2], Lb + 1024); \
    gl_lds(wb_ + o_ww[0], Lb + 1280); gl_lds(wb_ + o_ww[1], Lb + 1536); \
    gl_lds(tb_ + o_tt[0], Lb + 1792); gl_lds(tb_ + o_tt[1], Lb + 2048); \
    gl_lds(pb_ + o_tt[0], Lb + 2304); gl_lds(pb_ + o_tt[1], Lb + 2560); }

    float vzm = (z0 > 0) ? v[(size_t)(z0 - 1) * SV + vidx] : 0.f;
    float vc_r = v[(size_t)z0 * SV + vidx];

    for (int iz = 0; iz < UVZB; ++iz) {
        const int z = z0 + iz;
        V1_STAGE(z);
        float vzp = (z + 1 < NZ) ? v[(size_t)(z + 1) * SV + vidx] : 0.f;
        __syncthreads();

        const float* su  = lds;
        const float* svv = lds + 512;
        const float* sww = lds + 1280;
        const float* stt = lds + 1792;
        const float* spp = lds + 2304;
        {
            const float* pu_m = su + ty * 67;
            const float* pu_0 = su + (ty + 1) * 67;
            float F00 = Pxv[0][0]*pu_m[tx], F01 = Pxv[0][1]*pu_m[tx+1];
            float F02 = Pxv[0][2]*pu_m[tx+2], F03 = Pxv[0][3]*pu_m[tx+3];
            float F10 = Pxv[1][0]*pu_0[tx], F11 = Pxv[1][1]*pu_0[tx+1];
            float F12 = Pxv[1][2]*pu_0[tx+2], F13 = Pxv[1][3]*pu_0[tx+3];

            const float* pv0 = svv + (2 * ty + 0) * 66;
            const float* pv1 = svv + (2 * ty + 1) * 66;
            const float* pv2 = svv + (2 * ty + 2) * 66;
            const float* pv3 = svv + (2 * ty + 3) * 66;
            float V00 = pv0[tx], V01 = pv0[tx+1], V02 = pv0[tx+2];
            float V10 = pv1[tx], V11 = pv1[tx+1], V12 = pv1[tx+2];
            float V20 = pv2[tx], V21 = pv2[tx+1], V22 = pv2[tx+2];
            float V30 = pv3[tx], V31 = pv3[tx+1], V32 = pv3[tx+2];
            float G00 = Pgv[0][0]*V00, G01 = Pgv[0][1]*V01, G02 = Pgv[0][2]*V02;
            float G10 = Pgv[1][0]*V10, G11 = Pgv[1][1]*V11, G12 = Pgv[1][2]*V12;
            float G20 = Pgv[2][0]*V20, G21 = Pgv[2][1]*V21, G22 = Pgv[2][2]*V22;
            float G30 = Pgv[3][0]*V30, G31 = Pgv[3][1]*V31, G32 = Pgv[3][2]*V32;

            float vy_m = (yc < NY) ? V20 : V10;
            float vy_p = (yc < NY) ? V22 : V12;
            float vy_0 = vc_r;

            float Q_p = (F01 + F11 + F03 + F13) * K1;
            float Q_0 = (F00 + F10 + F02 + F12) * K1;
            float term1 = Q_0 * 0.5f * (vy_m + vy_0) - Q_p * 0.5f * (vy_0 + vy_p);

            float R_0 = (G20 + G30 + G22 + G32) * K1;
            float R_m = (G00 + G10 + G02 + G12) * K1;
            float term2 = R_m * 0.5f * (V01 + V11) - R_0 * 0.5f * (V21 + V31);

            float S_a = 0.25f * (G21 + G22 + G31 + G32) + (F11 + F13) * K2v;
            float S_b = 0.25f * (G00 + G01 + G10 + G11) + (F00 + F02) * K2v;
            float T_c = 0.25f * (G20 + G21 + G30 + G31) - (F10 + F12) * K2v;
            float T_d = 0.25f * (G01 + G02 + G11 + G12) - (F01 + F03) * K2v;
            float term3 = S_a * 0.25f * (V21 + V22 + V31 + V32) - S_b * 0.25f * (V00 + V01 + V10 + V11);
            float term4 = T_c * 0.25f * (V20 + V21 + V30 + V31) - T_d * 0.25f * (V01 + V02 + V11 + V12);
            float advec = 0.5f * (term1 + term2 + term3 + term4);

            float pw = pvmm * sww[ty * 66 + tx] + pv0m * sww[(ty + 1) * 66 + tx]
                     + pvmp * sww[ty * 66 + tx + 2] + pv0p * sww[(ty + 1) * 66 + tx + 2];
            float trans = -(DA8F * 0.25f * pw * 0.5f * (vzm + vzp) * 0.5f) * RDZF;

            float dphi = spp[(ty + 1) * 64 + tx] - spp[ty * 64 + tx];
            float vcz  = sigma[z] * (Pu[z] - Pp[z]) * RDZF;
            float vbar = 0.5f * (stt[ty * 64 + tx] + stt[(ty + 1) * 64 + tx]) * vcz;
            float press = DXF * (dphi * dpi * 0.5f + dpi * 0.5f * CPDF * vbar);

            float vlm = (yc > 0) ? V01 : V11;
            float vlp = (yc < NY) ? V31 : V21;
            float lap = vzp + vzm + vlp + vlm + vy_p + vy_m - 6.0f * vc_r;
            float diffv = DIFFF * lap;

            if (act) {
                size_t o = (size_t)z * SV + vidx;
                out[o] = (p0da * v0[o] + dt * (advec + trans + press + diffv)) * rp1da;
            }
            vzm = vc_r; vc_r = vzp;
        }
        __syncthreads();
    }
#undef V1_STAGE
}

extern "C" void kernel_launch(void* const* d_in, const int* in_sizes, int n_in,
                              void* d_out, int out_size, void* d_ws, size_t ws_size,
                              hipStream_t stream) {
    const float* pi    = (const float*)d_in[0];
    const float* theta = (const float*)d_in[1];
    const float* u     = (const float*)d_in[2];
    const float* v     = (const float*)d_in[3];
    const float* w     = (const float*)d_in[4];
    const float* phi   = (const float*)d_in[5];
    const float* Y     = (const float*)d_in[6];
    const float* sigma = (const float*)d_in[8];
    const float* P_    = (const float*)d_in[9];
    const float* P     = (const float*)d_in[10];
    const float* dtp   = (const float*)d_in[12];

    float* out_pi = (float*)d_out;
    float* out_th = out_pi + NY * NX;
    float* out_u  = out_th + NZ * NY * NX;
    float* out_v  = out_u + NZ * NY * NXU;

    float* ws   = (float*)d_ws;
    float* w_pi = ws;
    float* w_th = w_pi + NY * NX;
    float* w_u  = w_th + NZ * NY * NX;
    float* w_v  = w_u + NZ * NY * NXU;
    float* cyt  = w_v + NZ * NYV * NX;

    float* part = out_th;  // consumed by k_pi1_fin before k_theta1 writes out_th

    dim3 blk(256);
    dim3 blk2(64, 4);
    dim3 gpart(3, NY, PZ);
    dim3 gfin(3, NY);

    k_cosy<<<1, 512, 0, stream>>>(Y, cyt);

    // step 1: current = originals, state0 = originals, dt/2
    k_pi1_part<<<gpart, blk, 0, stream>>>(pi, u, v, cyt, part);
    k_pi1_fin<<<gfin, blk, 0, stream>>>(part, pi, dtp, 0.5f, w_pi);
    k_theta1<<<NBT, blk, 0, stream>>>(pi, theta, u, v, cyt, w, pi, theta, w_pi, dtp, 0.5f, w_th);
    k_u1<<<NBU, blk2, 0, stream>>>(pi, theta, u, v, cyt, w, phi, pi, u, w_pi, sigma, P_, P, dtp, 0.5f, w_u);
    k_v1<<<NBV, blk2, 0, stream>>>(pi, theta, u, v, cyt, w, phi, pi, v, w_pi, sigma, P_, P, dtp, 0.5f, w_v);

    // step 2: current = intermediates, state0 = originals, dt
    k_pi1_part<<<gpart, blk, 0, stream>>>(w_pi, w_u, w_v, cyt, part);
    k_pi1_fin<<<gfin, blk, 0, stream>>>(part, pi, dtp, 1.0f, out_pi);
    k_theta1<<<NBT, blk, 0, stream>>>(w_pi, w_th, w_u, w_v, cyt, w, pi, theta, out_pi, dtp, 1.0f, out_th);
    k_u1<<<NBU, blk2, 0, stream>>>(w_pi, w_th, w_u, w_v, cyt, w, phi, pi, u, out_pi, sigma, P_, P, dtp, 1.0f, out_u);
    k_v1<<<NBV, blk2, 0, stream>>>(w_pi, w_th, w_u, w_v, cyt, w, phi, pi, v, out_pi, sigma, P_, P, dtp, 1.0f, out_v);
}